// Round 19
// baseline (123.687 us; speedup 1.0000x reference)
//
#include <hip/hip_runtime.h>
#include <hip/hip_bf16.h>

#define B_ 2
#define T_ 2048
#define C_ 1024
#define H_ 16
#define DV_ 64
#define KW_ 31

typedef __attribute__((ext_vector_type(8))) short bf16x8;
typedef __attribute__((ext_vector_type(4))) short bf16x4;
typedef __attribute__((ext_vector_type(4))) float f32x4;

__device__ inline short f2bf(float f) {
    __hip_bfloat16 h = __float2bfloat16(f);
    return *reinterpret_cast<short*>(&h);
}
__device__ inline float bf2f(short s) {
    unsigned int u = ((unsigned int)(unsigned short)s) << 16;
    float f;
    __builtin_memcpy(&f, &u, 4);
    return f;
}

__device__ inline void async16(const void* g, void* l) {
    __builtin_amdgcn_global_load_lds(
        (const __attribute__((address_space(1))) unsigned int*)g,
        (__attribute__((address_space(3))) unsigned int*)l, 16, 0, 0);
}

__device__ inline void cvt8(const float* in, short* out, int i) {
    float4 v0 = ((const float4*)in)[i * 2];
    float4 v1 = ((const float4*)in)[i * 2 + 1];
    bf16x8 o;
    o[0] = f2bf(v0.x); o[1] = f2bf(v0.y); o[2] = f2bf(v0.z); o[3] = f2bf(v0.w);
    o[4] = f2bf(v1.x); o[5] = f2bf(v1.y); o[6] = f2bf(v1.z); o[7] = f2bf(v1.w);
    ((bf16x8*)out)[i] = o;
}

// ---------------------------------------------------------------- prep: xprep (0..1023) | w1 (1024..1535) | qk pack (1536..1567) | w2 (1568..2079) | w3 (2080..2591)
__global__ __launch_bounds__(256) void prep_kernel(
        const float* __restrict__ x, short* __restrict__ xbf, short* __restrict__ xvt,
        const float* __restrict__ w1, short* __restrict__ o1,
        const float* __restrict__ qw, const float* __restrict__ kw,
        short* __restrict__ qkw,
        const float* __restrict__ w2, const float* __restrict__ w3,
        short* __restrict__ o2, short* __restrict__ o3) {
    int bid = blockIdx.x;
    int tid = threadIdx.x;
    if (bid < 1024) {
        int bh = bid >> 5;
        int b = bh >> 4, h = bh & 15;
        int t0 = (bid & 31) * 64;
        __shared__ float ldsT[64][65];
        int tl = tid >> 2;
        int d0 = (tid & 3) * 16;
        const float* xp = x + ((size_t)(b * T_ + t0 + tl)) * C_ + h * 64 + d0;
        short* xbp = xbf + ((size_t)(b * T_ + t0 + tl)) * C_ + h * 64 + d0;
#pragma unroll
        for (int q = 0; q < 4; q++) {
            float4 v = *(const float4*)(xp + q * 4);
            ldsT[d0 + q * 4 + 0][tl] = v.x;
            ldsT[d0 + q * 4 + 1][tl] = v.y;
            ldsT[d0 + q * 4 + 2][tl] = v.z;
            ldsT[d0 + q * 4 + 3][tl] = v.w;
            bf16x4 ob;
            ob[0] = f2bf(v.x); ob[1] = f2bf(v.y); ob[2] = f2bf(v.z); ob[3] = f2bf(v.w);
            *(bf16x4*)(xbp + q * 4) = ob;
        }
        __syncthreads();
        int d = tid >> 2;
        int ts = (tid & 3) * 16;
        short* op = xvt + ((size_t)bh * 64 + d) * T_ + t0 + ts;
        bf16x8 o0, o1;
#pragma unroll
        for (int q = 0; q < 8; q++) {
            o0[q] = f2bf(ldsT[d][ts + q]);
            o1[q] = f2bf(ldsT[d][ts + 8 + q]);
        }
        *(bf16x8*)op = o0;
        *(bf16x8*)(op + 8) = o1;
    } else if (bid < 1536) {
        cvt8(w1, o1, (bid - 1024) * 256 + tid);
    } else if (bid < 1568) {
        int i = (bid - 1536) * 256 + tid;
        int n = i >> 7;
        int k8 = (i & 127) * 8;
        const float* src = (n < 32 ? qw + (size_t)n * C_ : kw + (size_t)(n - 32) * C_) + k8;
        float4 v0 = *(const float4*)src;
        float4 v1 = *(const float4*)(src + 4);
        bf16x8 o;
        o[0] = f2bf(v0.x); o[1] = f2bf(v0.y); o[2] = f2bf(v0.z); o[3] = f2bf(v0.w);
        o[4] = f2bf(v1.x); o[5] = f2bf(v1.y); o[6] = f2bf(v1.z); o[7] = f2bf(v1.w);
        ((bf16x8*)qkw)[i] = o;
    } else if (bid < 2080) {
        cvt8(w2, o2, (bid - 1568) * 256 + tid);
    } else {
        cvt8(w3, o3, (bid - 2080) * 256 + tid);
    }
}

// ---------------------------------------------------------------- q/k proj via MFMA (bf16 inputs, global_load_lds staging)
__global__ __launch_bounds__(256) void qkproj_kernel(
        const short* __restrict__ A, const short* __restrict__ Wq,
        const float* __restrict__ qbias, const float* __restrict__ kbias,
        float* __restrict__ qo, float* __restrict__ kbT) {
    __shared__ short At[128 * 32];
    __shared__ short Wt[64 * 32];
    int tid = threadIdx.x;
    int w = tid >> 6, l = tid & 63;
    int i0 = blockIdx.x * 128;
    int R0 = w * 32;
    const int xorb = (((l >> 4) ^ (l & 3)) << 4);
    int srow = l >> 2, schunk = l & 3;

    f32x4 acc[2][4];
#pragma unroll
    for (int m = 0; m < 2; m++)
#pragma unroll
        for (int n = 0; n < 4; n++) acc[m][n] = (f32x4){0.f, 0.f, 0.f, 0.f};

    for (int k0 = 0; k0 < C_; k0 += 32) {
#pragma unroll
        for (int half = 0; half < 2; half++) {
            int rr = half * 64 + w * 16 + srow;
            int gch = schunk ^ (rr & 3);
            async16((const char*)(A + (size_t)(i0 + rr) * C_ + k0) + gch * 16,
                    (char*)At + half * 4096 + w * 1024);
        }
        {
            int rr = w * 16 + srow;
            int gch = schunk ^ (rr & 3);
            async16((const char*)(Wq + (size_t)rr * C_ + k0) + gch * 16,
                    (char*)Wt + w * 1024);
        }
        __syncthreads();
        bf16x8 afr[2], bfr[4];
#pragma unroll
        for (int m = 0; m < 2; m++)
            afr[m] = *(const bf16x8*)((char*)At + (R0 + m * 16 + (l & 15)) * 64 + xorb);
#pragma unroll
        for (int n = 0; n < 4; n++)
            bfr[n] = *(const bf16x8*)((char*)Wt + (n * 16 + (l & 15)) * 64 + xorb);
#pragma unroll
        for (int m = 0; m < 2; m++)
#pragma unroll
            for (int n = 0; n < 4; n++)
                acc[m][n] = __builtin_amdgcn_mfma_f32_16x16x32_bf16(afr[m], bfr[n], acc[m][n], 0, 0, 0);
        __syncthreads();
    }
#pragma unroll
    for (int n = 0; n < 4; n++) {
        int col = n * 16 + (l & 15);
        float bj = (col < 32) ? qbias[col] : kbias[col - 32];
#pragma unroll
        for (int m = 0; m < 2; m++) {
            int rbase = i0 + R0 + m * 16 + ((l >> 4) << 2);
#pragma unroll
            for (int g = 0; g < 4; g++) {
                float z = acc[m][n][g] + bj;
                int row = rbase + g;
                if (col < 32) {
                    qo[(size_t)row * 32 + col] = z;
                } else {
                    int cc = col - 32, hh = cc >> 1, dd = cc & 1;
                    int bb_ = row >> 11, tt = row & (T_ - 1);
                    kbT[(((size_t)bb_ * 16 + hh) * 2 + dd) * T_ + tt] = z;
                }
            }
        }
    }
}

// ---------------------------------------------------------------- MEGA: attn (0..1535) | mgemm0 (1536..2047) | conv (2048..3071)
#define TCV 16
__global__ __launch_bounds__(256) void mega_kernel(
        const float* __restrict__ qbuf, const float* __restrict__ kbT,
        const short* __restrict__ xvt, short* __restrict__ xattb,
        short* __restrict__ partb, float* __restrict__ lpart,
        const short* __restrict__ xbf, const short* __restrict__ wbf1,
        const float* __restrict__ mem_b1, short* __restrict__ y1bf,
        const float* __restrict__ conv_w, const float* __restrict__ conv_b,
        short* __restrict__ xconvb) {
    __shared__ __align__(16) char smem[40960];
    int bid = blockIdx.x;
    int tid = threadIdx.x;
    int w = tid >> 6, l = tid & 63;
    int l15 = l & 15, l4 = l >> 4;

    if (bid < 1536) {
        // ===== attention, KV tile 128, KV-split CK=1024, no-max softmax =====
        int bh = bid & 31;
        int b = bh >> 4, h = bh & 15;
        int idx = 47 - (bid >> 5);
        int tb, ck;
        if (idx < 16) { tb = idx; ck = 0; }
        else          { tb = 16 + ((idx - 16) >> 1); ck = (idx - 16) & 1; }
        int t0 = tb * 64;
        int kvs = ck * 1024;
        int kve = min(kvs + 1024, t0 + 64);
        int ntiles = (kve - kvs + 127) >> 7;
        bool dom = (kve == t0 + 64);
        bool single = (tb < 16);
        char* Vb = smem;                      // 2 x 16KB
        char* Kb = smem + 32768;              // 8KB [2][1024] f32

        const float scale = 0.02209708691f * 1.44269504089f;  // 1/sqrt(T)*log2e
        int rloc = w * 16 + l15;
        float2 q2 = *(const float2*)(qbuf + ((size_t)(b * T_ + t0 + rloc)) * 32 + h * 2);
        float qx = q2.x * scale, qy = q2.y * scale;

        const uint4 onesu = {0x3F803F80u, 0x3F803F80u, 0x3F803F80u, 0x3F803F80u};
        bf16x8 ones = *(const bf16x8*)&onesu;

        f32x4 acc[4];
#pragma unroll
        for (int n = 0; n < 4; n++) acc[n] = (f32x4){0.f, 0.f, 0.f, 0.f};
        f32x4 acc_l = (f32x4){0.f, 0.f, 0.f, 0.f};

        // K chunk [2][1024] f32 staged once
        {
            int d = w >> 1, half = w & 1;
            char* kdst = Kb + d * 4096 + half * 2048;
            const char* ksrc = (const char*)(kbT + ((size_t)bh * 2 + d) * T_ + kvs)
                               + half * 2048 + l * 16;
            async16(ksrc, kdst);
            async16(ksrc + 1024, kdst + 1024);
        }
        // V staging: async j (0..3): dv = w*16 + j*4 + l4, slot = l15, src chunk c = l15 ^ (dv&15)
        const char* vsrc[4];
#pragma unroll
        for (int j = 0; j < 4; j++) {
            int dv = w * 16 + j * 4 + l4;
            int c = l15 ^ (dv & 15);
            vsrc[j] = (const char*)xvt + (((size_t)bh * 64 + dv) * T_ + (size_t)(kvs + c * 8)) * 2;
        }
#pragma unroll
        for (int j = 0; j < 4; j++)
            async16(vsrc[j], Vb + w * 4096 + j * 1024);

        const float* kl0 = (const float*)Kb;
        const float* kl1 = kl0 + 1024;

        for (int t = 0; t < ntiles; t++) {
            int buf = t & 1;
            __builtin_amdgcn_s_barrier();       // B1: prev reads of buf^1 done
            bool more = (t + 1 < ntiles);
            if (more) {
                size_t go = (size_t)((t + 1) * 128) * 2;
#pragma unroll
                for (int j = 0; j < 4; j++)
                    async16(vsrc[j] + go, Vb + (buf ^ 1) * 16384 + w * 4096 + j * 1024);
                asm volatile("s_waitcnt vmcnt(4)" ::: "memory");  // K + V(t) landed
            } else {
                asm volatile("s_waitcnt vmcnt(0)" ::: "memory");
            }
            __builtin_amdgcn_s_barrier();       // B2
            bool msk = dom && (t == ntiles - 1);
            int soff = kvs + t * 128 - t0;
            int locb = t * 128;
            bf16x8 afr[4];
#pragma unroll
            for (int ks = 0; ks < 4; ks++) {
                int lb = locb + ks * 32 + l4 * 8;
                float kx[8], ky[8];
                *(float4*)&kx[0] = *(const float4*)(kl0 + lb);
                *(float4*)&kx[4] = *(const float4*)(kl0 + lb + 4);
                *(float4*)&ky[0] = *(const float4*)(kl1 + lb);
                *(float4*)&ky[4] = *(const float4*)(kl1 + lb + 4);
                int kbase = soff + ks * 32 + l4 * 8;
                float pv[8];
#pragma unroll
                for (int i = 0; i < 8; i++) {
                    float sc = fmaf(qx, kx[i], qy * ky[i]);
                    float p = __builtin_amdgcn_exp2f(sc);
                    if (msk) p = (kbase + i <= rloc) ? p : 0.f;
                    pv[i] = p;
                }
                uint4 au;
                asm("v_cvt_pk_bf16_f32 %0, %1, %2" : "=v"(au.x) : "v"(pv[0]), "v"(pv[1]));
                asm("v_cvt_pk_bf16_f32 %0, %1, %2" : "=v"(au.y) : "v"(pv[2]), "v"(pv[3]));
                asm("v_cvt_pk_bf16_f32 %0, %1, %2" : "=v"(au.z) : "v"(pv[4]), "v"(pv[5]));
                asm("v_cvt_pk_bf16_f32 %0, %1, %2" : "=v"(au.w) : "v"(pv[6]), "v"(pv[7]));
                afr[ks] = *(bf16x8*)&au;
            }
            __builtin_amdgcn_s_setprio(1);
#pragma unroll
            for (int n = 0; n < 4; n++) {
                int dv = n * 16 + l15;
                int dvm = dv & 15;
#pragma unroll
                for (int ks = 0; ks < 4; ks++) {
                    int slot = (ks * 4 + l4) ^ dvm;
                    bf16x8 bv = *(const bf16x8*)(Vb + buf * 16384 + dv * 256 + slot * 16);
                    acc[n] = __builtin_amdgcn_mfma_f32_16x16x32_bf16(afr[ks], bv, acc[n], 0, 0, 0);
                }
            }
#pragma unroll
            for (int ks = 0; ks < 4; ks++)
                acc_l = __builtin_amdgcn_mfma_f32_16x16x32_bf16(afr[ks], ones, acc_l, 0, 0, 0);
            __builtin_amdgcn_s_setprio(0);
        }

        if (single) {
#pragma unroll
            for (int g = 0; g < 4; g++) {
                int row = w * 16 + l4 * 4 + g;
                float inv = 1.f / acc_l[g];
                int trow = t0 + row;
#pragma unroll
                for (int n = 0; n < 4; n++) {
                    int col = h * 64 + n * 16 + l15;
                    xattb[((size_t)(b * T_ + trow)) * C_ + col] = f2bf(acc[n][g] * inv);
                }
            }
        } else {
            int slot = bh * 32 + ((tb - 16) << 1) + ck;
            if (l15 == 0) {
#pragma unroll
                for (int g = 0; g < 4; g++)
                    lpart[(size_t)slot * 64 + w * 16 + l4 * 4 + g] = acc_l[g];
            }
            short* pp = partb + (size_t)slot * 4096;
#pragma unroll
            for (int g = 0; g < 4; g++) {
                int row = w * 16 + l4 * 4 + g;
#pragma unroll
                for (int n = 0; n < 4; n++)
                    pp[row * 64 + n * 16 + l15] = f2bf(acc[n][g]);
            }
        }
    } else if (bid < 2048) {
        // ===== mgemm0: y1 = silu(xbf*wbf1^T + b1), 128x64, BK=32, T4 pipeline =====
        int bid2 = bid - 1536;
        int i0 = (bid2 & 31) * 128;
        int j0 = (bid2 >> 5) * 64;
        int R0 = w * 32;
        const int xorb = ((l4 ^ (l & 3)) << 4);
        int srow = l >> 2, schunk = l & 3;
        char* Ab_ = smem;
        char* Wb_ = smem + 16384;

        f32x4 acc[2][4];
#pragma unroll
        for (int m = 0; m < 2; m++)
#pragma unroll
            for (int n = 0; n < 4; n++) acc[m][n] = (f32x4){0.f, 0.f, 0.f, 0.f};

#define GSTAGE0(buf_, k0_) do {                                                    \
    _Pragma("unroll") for (int half_ = 0; half_ < 2; half_++) {                    \
        int rr_ = half_ * 64 + w * 16 + srow;                                      \
        int gch_ = schunk ^ (rr_ & 3);                                             \
        async16((const char*)(xbf + (size_t)(i0 + rr_) * C_ + (k0_)) + gch_ * 16,  \
                Ab_ + (buf_) * 8192 + half_ * 4096 + w * 1024);                    \
    }                                                                              \
    { int rr_ = w * 16 + srow; int gch_ = schunk ^ (rr_ & 3);                      \
      async16((const char*)(wbf1 + (size_t)(j0 + rr_) * C_ + (k0_)) + gch_ * 16,   \
              Wb_ + (buf_) * 4096 + w * 1024); }                                   \
} while (0)

        GSTAGE0(0, 0);
        for (int ks = 0; ks < 32; ks++) {
            int buf = ks & 1;
            __builtin_amdgcn_s_barrier();
            if (ks + 1 < 32) {
                GSTAGE0(buf ^ 1, (ks + 1) * 32);
                asm volatile("s_waitcnt vmcnt(3)" ::: "memory");
            } else {
                asm volatile("s_waitcnt vmcnt(0)" ::: "memory");
            }
            __builtin_amdgcn_s_barrier();
            bf16x8 afr[2], bfr[4];
#pragma unroll
            for (int m = 0; m < 2; m++)
                afr[m] = *(const bf16x8*)(Ab_ + buf * 8192 + (R0 + m * 16 + l15) * 64 + xorb);
#pragma unroll
            for (int n = 0; n < 4; n++)
                bfr[n] = *(const bf16x8*)(Wb_ + buf * 4096 + (n * 16 + l15) * 64 + xorb);
            __builtin_amdgcn_s_setprio(1);
#pragma unroll
            for (int m = 0; m < 2; m++)
#pragma unroll
                for (int n = 0; n < 4; n++)
                    acc[m][n] = __builtin_amdgcn_mfma_f32_16x16x32_bf16(afr[m], bfr[n], acc[m][n], 0, 0, 0);
            __builtin_amdgcn_s_setprio(0);
        }
#undef GSTAGE0
#pragma unroll
        for (int n = 0; n < 4; n++) {
            int col = j0 + n * 16 + l15;
            float bj = mem_b1[col];
#pragma unroll
            for (int m = 0; m < 2; m++) {
                int rbase = i0 + R0 + m * 16 + l4 * 4;
#pragma unroll
                for (int g = 0; g < 4; g++) {
                    size_t off = (size_t)(rbase + g) * C_ + col;
                    float z = acc[m][n][g] + bj;
                    z = z / (1.f + __expf(-z));
                    y1bf[off] = f2bf(z);
                }
            }
        }
    } else {
        // ===== conv: depthwise K=31, register sliding window =====
        int cb = bid - 2048;
        int tblk = cb & 127;
        int rest = cb >> 7;
        int b = rest >> 2;
        int c0 = (rest & 3) * 256;
        int t0 = tblk * TCV;
        int c = c0 + tid;
        float wr[KW_];
        const float* wp = conv_w + (size_t)c * KW_;
#pragma unroll
        for (int k = 0; k < KW_; k++) wr[k] = wp[k];
        float bi = conv_b[c];
        float acc[TCV];
#pragma unroll
        for (int t = 0; t < TCV; t++) acc[t] = bi;
        const short* xp = xbf + (size_t)b * T_ * C_ + c;
#pragma unroll
        for (int i = 0; i < TCV + KW_ - 1; i++) {
            int tt = t0 + i - 15;
            float xv = (tt >= 0 && tt < T_) ? bf2f(xp[(size_t)tt * C_]) : 0.f;
            int lo = (i - (KW_ - 1) > 0) ? i - (KW_ - 1) : 0;
            int hi = (i < TCV - 1) ? i : TCV - 1;
#pragma unroll
            for (int t = lo; t <= hi; t++)
                acc[t] = fmaf(xv, wr[i - t], acc[t]);
        }
        short* op = xconvb + ((size_t)b * T_ + t0) * C_ + c;
#pragma unroll
        for (int t = 0; t < TCV; t++) op[(size_t)t * C_] = f2bf(acc[t]);
    }
}

// ---------------------------------------------------------------- bf16 MFMA GEMM  out = A(M,K)*W(N,K)^T
// tile 128x64, BK=64, double-buffered, counted-vmcnt + raw-barrier pipeline.
// MODE 1: comb epilogue with fused 2-chunk attn-combine (bf16 partials).
template <int MODE>
__global__ __launch_bounds__(256) void mgemm_kernel(
        const short* __restrict__ A, const short* __restrict__ W,
        const float* __restrict__ bias, short* __restrict__ outb,
        const short* __restrict__ e0, const short* __restrict__ e1,
        const short* __restrict__ e2, const float* __restrict__ e3,
        const short* __restrict__ partb, const float* __restrict__ lpart) {
    __shared__ short At[2 * 128 * 64];
    __shared__ short Wt[2 * 64 * 64];
    int tid = threadIdx.x;
    int w = tid >> 6, l = tid & 63;
    int l15 = l & 15, l4 = l >> 4;
    int i0 = ((int)blockIdx.x & 31) * 128;
    int j0 = ((int)blockIdx.x >> 5) * 64;
    int R0 = w * 32;
    int srow8 = l >> 3, sch = l & 7;
    const char* aptr[4];
#pragma unroll
    for (int q = 0; q < 4; q++) {
        int r = q * 32 + w * 8 + srow8;
        aptr[q] = (const char*)(A + (size_t)(i0 + r) * C_) + ((sch ^ (r & 7)) * 16);
    }
    const char* wptr[2];
#pragma unroll
    for (int q = 0; q < 2; q++) {
        int r = q * 32 + w * 8 + srow8;
        wptr[q] = (const char*)(W + (size_t)(j0 + r) * C_) + ((sch ^ (r & 7)) * 16);
    }
    char* Ab = (char*)At;
    char* Wb = (char*)Wt;

    f32x4 acc[2][4];
#pragma unroll
    for (int m = 0; m < 2; m++)
#pragma unroll
        for (int n = 0; n < 4; n++) acc[m][n] = (f32x4){0.f, 0.f, 0.f, 0.f};

#define GSTAGE(buf_, ks_) do {                                                 \
    size_t go_ = (size_t)(ks_) * 128;                                          \
    _Pragma("unroll") for (int q_ = 0; q_ < 4; q_++)                           \
        async16(aptr[q_] + go_, Ab + (buf_) * 16384 + q_ * 4096 + w * 1024);   \
    _Pragma("unroll") for (int q_ = 0; q_ < 2; q_++)                           \
        async16(wptr[q_] + go_, Wb + (buf_) * 8192 + q_ * 4096 + w * 1024);    \
} while (0)

    GSTAGE(0, 0);
    for (int ks = 0; ks < 16; ks++) {
        int buf = ks & 1;
        __builtin_amdgcn_s_barrier();
        if (ks + 1 < 16) {
            GSTAGE(buf ^ 1, ks + 1);
            asm volatile("s_waitcnt vmcnt(6)" ::: "memory");
        } else {
            asm volatile("s_waitcnt vmcnt(0)" ::: "memory");
        }
        __builtin_amdgcn_s_barrier();
        bf16x8 afr[2][2], bfr[4][2];
#pragma unroll
        for (int m = 0; m < 2; m++) {
            int r = R0 + m * 16 + l15;
#pragma unroll
            for (int s = 0; s < 2; s++)
                afr[m][s] = *(const bf16x8*)(Ab + buf * 16384 + r * 128 + (((s * 4 + l4) ^ (r & 7)) * 16));
        }
#pragma unroll
        for (int n = 0; n < 4; n++) {
            int r = n * 16 + l15;
#pragma unroll
            for (int s = 0; s < 2; s++)
                bfr[n][s] = *(const bf16x8*)(Wb + buf * 8192 + r * 128 + (((s * 4 + l4) ^ (r & 7)) * 16));
        }
        __builtin_amdgcn_s_setprio(1);
#pragma unroll
        for (int m = 0; m < 2; m++)
#pragma unroll
            for (int n = 0; n < 4; n++) {
                acc[m][n] = __builtin_amdgcn_mfma_f32_16x16x32_bf16(afr[m][0], bfr[n][0], acc[m][n], 0, 0, 0);
                acc[m][n] = __builtin_amdgcn_mfma_f32_16x16x32_bf16(afr[m][1], bfr[n][1], acc[m][n], 0, 0, 0);
            }
        __builtin_amdgcn_s_setprio(0);
    }
#undef GSTAGE
    // epilogue
    if (MODE == 1) {
        bool combrows = ((i0 & 2047) >= 1024);
        int b_ = i0 >> 11;
        int bh_ = b_ * 16 + (j0 >> 6);
#pragma unroll
        for (int m = 0; m < 2; m++) {
#pragma unroll
            for (int g = 0; g < 4; g++) {
                int row = i0 + R0 + m * 16 + l4 * 4 + g;
                int t_ = row & 2047;
                float xv[4];
                if (combrows) {
                    int s0_ = bh_ * 32 + (((t_ >> 6) - 16) << 1);
                    int r64 = t_ & 63;
                    float lt = lpart[(size_t)s0_ * 64 + r64] + lpart[(size_t)(s0_ + 1) * 64 + r64];
                    float li = 1.f / lt;
                    const short* p0 = partb + (size_t)s0_ * 4096 + r64 * 64;
                    const short* p1 = p0 + 4096;
#pragma unroll
                    for (int n = 0; n < 4; n++) {
                        int dv = n * 16 + l15;
                        xv[n] = (bf2f(p0[dv]) + bf2f(p1[dv])) * li;
                    }
                } else {
#pragma unroll
                    for (int n = 0; n < 4; n++)
                        xv[n] = bf2f(e1[(size_t)row * C_ + j0 + n * 16 + l15]);
                }
#pragma unroll
                for (int n = 0; n < 4; n++) {
                    int col = j0 + n * 16 + l15;
                    size_t off = (size_t)row * C_ + col;
                    float tdv = e3[col];
                    float z = acc[m][n][g] + bias[col];
                    float comb = bf2f(e0[off]) + 0.5f * xv[n] + 0.5f * z;
                    z = comb * tdv + bf2f(e2[off]) * (1.f - tdv);
                    outb[off] = f2bf(z);
                }
            }
        }
    } else {
#pragma unroll
        for (int n = 0; n < 4; n++) {
            int col = j0 + n * 16 + l15;
            float bj = bias[col];
#pragma unroll
            for (int m = 0; m < 2; m++) {
                int rbase = i0 + R0 + m * 16 + l4 * 4;
#pragma unroll
                for (int g = 0; g < 4; g++) {
                    size_t off = (size_t)(rbase + g) * C_ + col;
                    float z = acc[m][n][g] + bj;
                    if (MODE == 0) z = z / (1.f + __expf(-z));
                    outb[off] = f2bf(z);
                }
            }
        }
    }
}

// ---------------------------------------------------------------- layernorm + residual
__global__ __launch_bounds__(256) void ln_kernel(
        const short* __restrict__ proj, const short* __restrict__ xb,
        const float* __restrict__ g, const float* __restrict__ bb,
        float* __restrict__ out) {
    int row = blockIdx.x;
    int tid = threadIdx.x;
    const short* pr = proj + (size_t)row * C_;
    bf16x4 pv = *(const bf16x4*)(pr + tid * 4);
    float4 v = make_float4(bf2f(pv[0]), bf2f(pv[1]), bf2f(pv[2]), bf2f(pv[3]));
    float s = v.x + v.y + v.z + v.w;
    float s2 = v.x * v.x + v.y * v.y + v.z * v.z + v.w * v.w;
#pragma unroll
    for (int off = 32; off > 0; off >>= 1) {
        s += __shfl_down(s, off);
        s2 += __shfl_down(s2, off);
    }
    __shared__ float ws0[4], ws1[4];
    int wid = tid >> 6;
    if ((tid & 63) == 0) { ws0[wid] = s; ws1[wid] = s2; }
    __syncthreads();
    s = ws0[0] + ws0[1] + ws0[2] + ws0[3];
    s2 = ws1[0] + ws1[1] + ws1[2] + ws1[3];
    float mu = s * (1.f / C_);
    float var = s2 * (1.f / C_) - mu * mu;
    float rs = rsqrtf(var + 1e-5f);
    int c = tid * 4;
    bf16x4 xr4 = *(const bf16x4*)(xb + (size_t)row * C_ + c);
    float4 gg = *(const float4*)(g + c);
    float4 bv = *(const float4*)(bb + c);
    float4 o;
    o.x = (v.x - mu) * rs * gg.x + bv.x + bf2f(xr4[0]);
    o.y = (v.y - mu) * rs * gg.y + bv.y + bf2f(xr4[1]);
    o.z = (v.z - mu) * rs * gg.z + bv.z + bf2f(xr4[2]);
    o.w = (v.w - mu) * rs * gg.w + bv.w + bf2f(xr4[3]);
    *(float4*)(out + (size_t)row * C_ + c) = o;
}

// ---------------------------------------------------------------- launch
extern "C" void kernel_launch(void* const* d_in, const int* in_sizes, int n_in,
                              void* d_out, int out_size, void* d_ws, size_t ws_size,
                              hipStream_t stream) {
    const float* x      = (const float*)d_in[0];
    const float* conv_w = (const float*)d_in[1];
    const float* conv_b = (const float*)d_in[2];
    const float* q_w    = (const float*)d_in[3];
    const float* q_b    = (const float*)d_in[4];
    const float* kv_w   = (const float*)d_in[5];
    const float* kv_b   = (const float*)d_in[6];
    const float* mem_w1 = (const float*)d_in[7];
    const float* mem_b1 = (const float*)d_in[8];
    const float* mem_w2 = (const float*)d_in[9];
    const float* mem_b2 = (const float*)d_in[10];
    const float* out_w  = (const float*)d_in[11];
    const float* out_b  = (const float*)d_in[12];
    const float* ln_g   = (const float*)d_in[13];
    const float* ln_b   = (const float*)d_in[14];
    const float* td     = (const float*)d_in[15];
    float* out = (float*)d_out;

    const size_t NTC = (size_t)B_ * T_ * C_;
    char* p = (char*)d_ws;
    short* xconvb = (short*)p;           p += NTC * 2;
    short* xattb  = (short*)p;           p += NTC * 2;
    float* qb_   = (float*)p;            p += (size_t)B_ * T_ * 32 * 4;
    float* kbT   = (float*)p;            p += (size_t)B_ * H_ * 2 * T_ * 4;
    short* xbf   = (short*)p;            p += NTC * 2;
    short* y1bf  = (short*)p;            p += NTC * 2;
    short* combbf= (short*)p;            p += NTC * 2;
    short* xvt   = (short*)p;            p += NTC * 2;
    short* projb = (short*)p;            p += NTC * 2;
    short* wbf1  = (short*)p;            p += (size_t)C_ * C_ * 2;
    short* wbf2  = (short*)p;            p += (size_t)C_ * C_ * 2;
    short* wbf3  = (short*)p;            p += (size_t)C_ * C_ * 2;
    short* qkw   = (short*)p;            p += (size_t)64 * C_ * 2;
    short* partb = (short*)p;            p += (size_t)1024 * 4096 * 2;
    float* lpart = (float*)p;            p += (size_t)1024 * 64 * 4;

    prep_kernel<<<2592, 256, 0, stream>>>(x, xbf, xvt, mem_w1, wbf1, q_w, kv_w, qkw,
                                          mem_w2, out_w, wbf2, wbf3);
    qkproj_kernel<<<(B_ * T_) / 128, 256, 0, stream>>>(xbf, qkw, q_b, kv_b, qb_, kbT);
    mega_kernel<<<3072, 256, 0, stream>>>(qb_, kbT, xvt, xattb, partb, lpart,
                                          xbf, wbf1, mem_b1, y1bf,
                                          conv_w, conv_b, xconvb);
    mgemm_kernel<1><<<512, 256, 0, stream>>>(
        y1bf, wbf2, mem_b2, combbf, xconvb, xattb, xbf, td, partb, lpart);
    mgemm_kernel<2><<<512, 256, 0, stream>>>(
        combbf, wbf3, out_b, projb, nullptr, nullptr, nullptr, nullptr, nullptr, nullptr);
    ln_kernel<<<B_ * T_, 256, 0, stream>>>(projb, xbf, ln_g, ln_b, out);
}

// Round 20
// 123.506 us; speedup vs baseline: 1.0015x; 1.0015x over previous
//
#include <hip/hip_runtime.h>
#include <hip/hip_bf16.h>

#define B_ 2
#define T_ 2048
#define C_ 1024
#define H_ 16
#define DV_ 64
#define KW_ 31

typedef __attribute__((ext_vector_type(8))) short bf16x8;
typedef __attribute__((ext_vector_type(4))) short bf16x4;
typedef __attribute__((ext_vector_type(4))) float f32x4;

__device__ inline short f2bf(float f) {
    __hip_bfloat16 h = __float2bfloat16(f);
    return *reinterpret_cast<short*>(&h);
}
__device__ inline float bf2f(short s) {
    unsigned int u = ((unsigned int)(unsigned short)s) << 16;
    float f;
    __builtin_memcpy(&f, &u, 4);
    return f;
}

__device__ inline void async16(const void* g, void* l) {
    __builtin_amdgcn_global_load_lds(
        (const __attribute__((address_space(1))) unsigned int*)g,
        (__attribute__((address_space(3))) unsigned int*)l, 16, 0, 0);
}

__device__ inline void cvt8(const float* in, short* out, int i) {
    float4 v0 = ((const float4*)in)[i * 2];
    float4 v1 = ((const float4*)in)[i * 2 + 1];
    bf16x8 o;
    o[0] = f2bf(v0.x); o[1] = f2bf(v0.y); o[2] = f2bf(v0.z); o[3] = f2bf(v0.w);
    o[4] = f2bf(v1.x); o[5] = f2bf(v1.y); o[6] = f2bf(v1.z); o[7] = f2bf(v1.w);
    ((bf16x8*)out)[i] = o;
}

// ---------------------------------------------------------------- prep: xprep (0..1023) | w1 cvt (1024..1535) | qk pack (1536..1567)
__global__ __launch_bounds__(256) void prep_kernel(
        const float* __restrict__ x, short* __restrict__ xbf, short* __restrict__ xvt,
        const float* __restrict__ w1, short* __restrict__ o1,
        const float* __restrict__ qw, const float* __restrict__ kw,
        short* __restrict__ qkw) {
    int bid = blockIdx.x;
    int tid = threadIdx.x;
    if (bid < 1024) {
        int bh = bid >> 5;
        int b = bh >> 4, h = bh & 15;
        int t0 = (bid & 31) * 64;
        __shared__ float ldsT[64][65];
        int tl = tid >> 2;
        int d0 = (tid & 3) * 16;
        const float* xp = x + ((size_t)(b * T_ + t0 + tl)) * C_ + h * 64 + d0;
        short* xbp = xbf + ((size_t)(b * T_ + t0 + tl)) * C_ + h * 64 + d0;
#pragma unroll
        for (int q = 0; q < 4; q++) {
            float4 v = *(const float4*)(xp + q * 4);
            ldsT[d0 + q * 4 + 0][tl] = v.x;
            ldsT[d0 + q * 4 + 1][tl] = v.y;
            ldsT[d0 + q * 4 + 2][tl] = v.z;
            ldsT[d0 + q * 4 + 3][tl] = v.w;
            bf16x4 ob;
            ob[0] = f2bf(v.x); ob[1] = f2bf(v.y); ob[2] = f2bf(v.z); ob[3] = f2bf(v.w);
            *(bf16x4*)(xbp + q * 4) = ob;
        }
        __syncthreads();
        int d = tid >> 2;
        int ts = (tid & 3) * 16;
        short* op = xvt + ((size_t)bh * 64 + d) * T_ + t0 + ts;
        bf16x8 o0, o1;
#pragma unroll
        for (int q = 0; q < 8; q++) {
            o0[q] = f2bf(ldsT[d][ts + q]);
            o1[q] = f2bf(ldsT[d][ts + 8 + q]);
        }
        *(bf16x8*)op = o0;
        *(bf16x8*)(op + 8) = o1;
    } else if (bid < 1536) {
        cvt8(w1, o1, (bid - 1024) * 256 + tid);
    } else {
        int i = (bid - 1536) * 256 + tid;
        int n = i >> 7;
        int k8 = (i & 127) * 8;
        const float* src = (n < 32 ? qw + (size_t)n * C_ : kw + (size_t)(n - 32) * C_) + k8;
        float4 v0 = *(const float4*)src;
        float4 v1 = *(const float4*)(src + 4);
        bf16x8 o;
        o[0] = f2bf(v0.x); o[1] = f2bf(v0.y); o[2] = f2bf(v0.z); o[3] = f2bf(v0.w);
        o[4] = f2bf(v1.x); o[5] = f2bf(v1.y); o[6] = f2bf(v1.z); o[7] = f2bf(v1.w);
        ((bf16x8*)qkw)[i] = o;
    }
}

// ---------------------------------------------------------------- q/k proj via MFMA (bf16 inputs, global_load_lds staging)
__global__ __launch_bounds__(256) void qkproj_kernel(
        const short* __restrict__ A, const short* __restrict__ Wq,
        const float* __restrict__ qbias, const float* __restrict__ kbias,
        float* __restrict__ qo, float* __restrict__ kbT) {
    __shared__ short At[128 * 32];
    __shared__ short Wt[64 * 32];
    int tid = threadIdx.x;
    int w = tid >> 6, l = tid & 63;
    int i0 = blockIdx.x * 128;
    int R0 = w * 32;
    const int xorb = (((l >> 4) ^ (l & 3)) << 4);
    int srow = l >> 2, schunk = l & 3;

    f32x4 acc[2][4];
#pragma unroll
    for (int m = 0; m < 2; m++)
#pragma unroll
        for (int n = 0; n < 4; n++) acc[m][n] = (f32x4){0.f, 0.f, 0.f, 0.f};

    for (int k0 = 0; k0 < C_; k0 += 32) {
#pragma unroll
        for (int half = 0; half < 2; half++) {
            int rr = half * 64 + w * 16 + srow;
            int gch = schunk ^ (rr & 3);
            async16((const char*)(A + (size_t)(i0 + rr) * C_ + k0) + gch * 16,
                    (char*)At + half * 4096 + w * 1024);
        }
        {
            int rr = w * 16 + srow;
            int gch = schunk ^ (rr & 3);
            async16((const char*)(Wq + (size_t)rr * C_ + k0) + gch * 16,
                    (char*)Wt + w * 1024);
        }
        __syncthreads();
        bf16x8 afr[2], bfr[4];
#pragma unroll
        for (int m = 0; m < 2; m++)
            afr[m] = *(const bf16x8*)((char*)At + (R0 + m * 16 + (l & 15)) * 64 + xorb);
#pragma unroll
        for (int n = 0; n < 4; n++)
            bfr[n] = *(const bf16x8*)((char*)Wt + (n * 16 + (l & 15)) * 64 + xorb);
#pragma unroll
        for (int m = 0; m < 2; m++)
#pragma unroll
            for (int n = 0; n < 4; n++)
                acc[m][n] = __builtin_amdgcn_mfma_f32_16x16x32_bf16(afr[m], bfr[n], acc[m][n], 0, 0, 0);
        __syncthreads();
    }
#pragma unroll
    for (int n = 0; n < 4; n++) {
        int col = n * 16 + (l & 15);
        float bj = (col < 32) ? qbias[col] : kbias[col - 32];
#pragma unroll
        for (int m = 0; m < 2; m++) {
            int rbase = i0 + R0 + m * 16 + ((l >> 4) << 2);
#pragma unroll
            for (int g = 0; g < 4; g++) {
                float z = acc[m][n][g] + bj;
                int row = rbase + g;
                if (col < 32) {
                    qo[(size_t)row * 32 + col] = z;
                } else {
                    int cc = col - 32, hh = cc >> 1, dd = cc & 1;
                    int bb_ = row >> 11, tt = row & (T_ - 1);
                    kbT[(((size_t)bb_ * 16 + hh) * 2 + dd) * T_ + tt] = z;
                }
            }
        }
    }
}

// ---------------------------------------------------------------- MEGA: attn (0..1535) | mgemm0 (1536..2047) | conv (2048..2559) | w2/w3 cvt (2560..3583)
#define TCV 32
__global__ __launch_bounds__(256) void mega_kernel(
        const float* __restrict__ qbuf, const float* __restrict__ kbT,
        const short* __restrict__ xvt, short* __restrict__ xattb,
        short* __restrict__ partb, float* __restrict__ lpart,
        const short* __restrict__ xbf, const short* __restrict__ wbf1,
        const float* __restrict__ mem_b1, short* __restrict__ y1bf,
        const float* __restrict__ conv_w, const float* __restrict__ conv_b,
        short* __restrict__ xconvb,
        const float* __restrict__ w2, const float* __restrict__ w3,
        short* __restrict__ o2, short* __restrict__ o3) {
    __shared__ __align__(16) char smem[40960];
    int bid = blockIdx.x;
    int tid = threadIdx.x;
    int w = tid >> 6, l = tid & 63;
    int l15 = l & 15, l4 = l >> 4;

    if (bid < 1536) {
        // ===== attention, KV tile 128, KV-split CK=1024, no-max softmax =====
        int bh = bid & 31;
        int b = bh >> 4, h = bh & 15;
        int idx = 47 - (bid >> 5);
        int tb, ck;
        if (idx < 16) { tb = idx; ck = 0; }
        else          { tb = 16 + ((idx - 16) >> 1); ck = (idx - 16) & 1; }
        int t0 = tb * 64;
        int kvs = ck * 1024;
        int kve = min(kvs + 1024, t0 + 64);
        int ntiles = (kve - kvs + 127) >> 7;
        bool dom = (kve == t0 + 64);
        bool single = (tb < 16);
        char* Vb = smem;                      // 2 x 16KB
        char* Kb = smem + 32768;              // 8KB [2][1024] f32

        const float scale = 0.02209708691f * 1.44269504089f;  // 1/sqrt(T)*log2e
        int rloc = w * 16 + l15;
        float2 q2 = *(const float2*)(qbuf + ((size_t)(b * T_ + t0 + rloc)) * 32 + h * 2);
        float qx = q2.x * scale, qy = q2.y * scale;

        const uint4 onesu = {0x3F803F80u, 0x3F803F80u, 0x3F803F80u, 0x3F803F80u};
        bf16x8 ones = *(const bf16x8*)&onesu;

        f32x4 acc[4];
#pragma unroll
        for (int n = 0; n < 4; n++) acc[n] = (f32x4){0.f, 0.f, 0.f, 0.f};
        f32x4 acc_l = (f32x4){0.f, 0.f, 0.f, 0.f};

        // K chunk [2][1024] f32 staged once
        {
            int d = w >> 1, half = w & 1;
            char* kdst = Kb + d * 4096 + half * 2048;
            const char* ksrc = (const char*)(kbT + ((size_t)bh * 2 + d) * T_ + kvs)
                               + half * 2048 + l * 16;
            async16(ksrc, kdst);
            async16(ksrc + 1024, kdst + 1024);
        }
        // V staging: async j (0..3): dv = w*16 + j*4 + l4, slot = l15, src chunk c = l15 ^ (dv&15)
        const char* vsrc[4];
#pragma unroll
        for (int j = 0; j < 4; j++) {
            int dv = w * 16 + j * 4 + l4;
            int c = l15 ^ (dv & 15);
            vsrc[j] = (const char*)xvt + (((size_t)bh * 64 + dv) * T_ + (size_t)(kvs + c * 8)) * 2;
        }
#pragma unroll
        for (int j = 0; j < 4; j++)
            async16(vsrc[j], Vb + w * 4096 + j * 1024);

        const float* kl0 = (const float*)Kb;
        const float* kl1 = kl0 + 1024;

        for (int t = 0; t < ntiles; t++) {
            int buf = t & 1;
            __builtin_amdgcn_s_barrier();       // B1: prev reads of buf^1 done
            bool more = (t + 1 < ntiles);
            if (more) {
                size_t go = (size_t)((t + 1) * 128) * 2;
#pragma unroll
                for (int j = 0; j < 4; j++)
                    async16(vsrc[j] + go, Vb + (buf ^ 1) * 16384 + w * 4096 + j * 1024);
                asm volatile("s_waitcnt vmcnt(4)" ::: "memory");  // K + V(t) landed
            } else {
                asm volatile("s_waitcnt vmcnt(0)" ::: "memory");
            }
            __builtin_amdgcn_s_barrier();       // B2
            bool msk = dom && (t == ntiles - 1);
            int soff = kvs + t * 128 - t0;
            int locb = t * 128;
            bf16x8 afr[4];
#pragma unroll
            for (int ks = 0; ks < 4; ks++) {
                int lb = locb + ks * 32 + l4 * 8;
                float kx[8], ky[8];
                *(float4*)&kx[0] = *(const float4*)(kl0 + lb);
                *(float4*)&kx[4] = *(const float4*)(kl0 + lb + 4);
                *(float4*)&ky[0] = *(const float4*)(kl1 + lb);
                *(float4*)&ky[4] = *(const float4*)(kl1 + lb + 4);
                int kbase = soff + ks * 32 + l4 * 8;
                float pv[8];
#pragma unroll
                for (int i = 0; i < 8; i++) {
                    float sc = fmaf(qx, kx[i], qy * ky[i]);
                    float p = __builtin_amdgcn_exp2f(sc);
                    if (msk) p = (kbase + i <= rloc) ? p : 0.f;
                    pv[i] = p;
                }
                uint4 au;
                asm("v_cvt_pk_bf16_f32 %0, %1, %2" : "=v"(au.x) : "v"(pv[0]), "v"(pv[1]));
                asm("v_cvt_pk_bf16_f32 %0, %1, %2" : "=v"(au.y) : "v"(pv[2]), "v"(pv[3]));
                asm("v_cvt_pk_bf16_f32 %0, %1, %2" : "=v"(au.z) : "v"(pv[4]), "v"(pv[5]));
                asm("v_cvt_pk_bf16_f32 %0, %1, %2" : "=v"(au.w) : "v"(pv[6]), "v"(pv[7]));
                afr[ks] = *(bf16x8*)&au;
            }
            __builtin_amdgcn_s_setprio(1);
#pragma unroll
            for (int n = 0; n < 4; n++) {
                int dv = n * 16 + l15;
                int dvm = dv & 15;
#pragma unroll
                for (int ks = 0; ks < 4; ks++) {
                    int slot = (ks * 4 + l4) ^ dvm;
                    bf16x8 bv = *(const bf16x8*)(Vb + buf * 16384 + dv * 256 + slot * 16);
                    acc[n] = __builtin_amdgcn_mfma_f32_16x16x32_bf16(afr[ks], bv, acc[n], 0, 0, 0);
                }
            }
#pragma unroll
            for (int ks = 0; ks < 4; ks++)
                acc_l = __builtin_amdgcn_mfma_f32_16x16x32_bf16(afr[ks], ones, acc_l, 0, 0, 0);
            __builtin_amdgcn_s_setprio(0);
        }

        if (single) {
#pragma unroll
            for (int g = 0; g < 4; g++) {
                int row = w * 16 + l4 * 4 + g;
                float inv = 1.f / acc_l[g];
                int trow = t0 + row;
#pragma unroll
                for (int n = 0; n < 4; n++) {
                    int col = h * 64 + n * 16 + l15;
                    xattb[((size_t)(b * T_ + trow)) * C_ + col] = f2bf(acc[n][g] * inv);
                }
            }
        } else {
            int slot = bh * 32 + ((tb - 16) << 1) + ck;
            if (l15 == 0) {
#pragma unroll
                for (int g = 0; g < 4; g++)
                    lpart[(size_t)slot * 64 + w * 16 + l4 * 4 + g] = acc_l[g];
            }
            short* pp = partb + (size_t)slot * 4096;
#pragma unroll
            for (int g = 0; g < 4; g++) {
                int row = w * 16 + l4 * 4 + g;
#pragma unroll
                for (int n = 0; n < 4; n++)
                    pp[row * 64 + n * 16 + l15] = f2bf(acc[n][g]);
            }
        }
    } else if (bid < 2048) {
        // ===== mgemm0: y1 = silu(xbf*wbf1^T + b1), 128x64, BK=32, T4 pipeline =====
        int bid2 = bid - 1536;
        int i0 = (bid2 & 31) * 128;
        int j0 = (bid2 >> 5) * 64;
        int R0 = w * 32;
        const int xorb = ((l4 ^ (l & 3)) << 4);
        int srow = l >> 2, schunk = l & 3;
        char* Ab_ = smem;
        char* Wb_ = smem + 16384;

        f32x4 acc[2][4];
#pragma unroll
        for (int m = 0; m < 2; m++)
#pragma unroll
            for (int n = 0; n < 4; n++) acc[m][n] = (f32x4){0.f, 0.f, 0.f, 0.f};

#define GSTAGE0(buf_, k0_) do {                                                    \
    _Pragma("unroll") for (int half_ = 0; half_ < 2; half_++) {                    \
        int rr_ = half_ * 64 + w * 16 + srow;                                      \
        int gch_ = schunk ^ (rr_ & 3);                                             \
        async16((const char*)(xbf + (size_t)(i0 + rr_) * C_ + (k0_)) + gch_ * 16,  \
                Ab_ + (buf_) * 8192 + half_ * 4096 + w * 1024);                    \
    }                                                                              \
    { int rr_ = w * 16 + srow; int gch_ = schunk ^ (rr_ & 3);                      \
      async16((const char*)(wbf1 + (size_t)(j0 + rr_) * C_ + (k0_)) + gch_ * 16,   \
              Wb_ + (buf_) * 4096 + w * 1024); }                                   \
} while (0)

        GSTAGE0(0, 0);
        for (int ks = 0; ks < 32; ks++) {
            int buf = ks & 1;
            __builtin_amdgcn_s_barrier();
            if (ks + 1 < 32) {
                GSTAGE0(buf ^ 1, (ks + 1) * 32);
                asm volatile("s_waitcnt vmcnt(3)" ::: "memory");
            } else {
                asm volatile("s_waitcnt vmcnt(0)" ::: "memory");
            }
            __builtin_amdgcn_s_barrier();
            bf16x8 afr[2], bfr[4];
#pragma unroll
            for (int m = 0; m < 2; m++)
                afr[m] = *(const bf16x8*)(Ab_ + buf * 8192 + (R0 + m * 16 + l15) * 64 + xorb);
#pragma unroll
            for (int n = 0; n < 4; n++)
                bfr[n] = *(const bf16x8*)(Wb_ + buf * 4096 + (n * 16 + l15) * 64 + xorb);
            __builtin_amdgcn_s_setprio(1);
#pragma unroll
            for (int m = 0; m < 2; m++)
#pragma unroll
                for (int n = 0; n < 4; n++)
                    acc[m][n] = __builtin_amdgcn_mfma_f32_16x16x32_bf16(afr[m], bfr[n], acc[m][n], 0, 0, 0);
            __builtin_amdgcn_s_setprio(0);
        }
#undef GSTAGE0
#pragma unroll
        for (int n = 0; n < 4; n++) {
            int col = j0 + n * 16 + l15;
            float bj = mem_b1[col];
#pragma unroll
            for (int m = 0; m < 2; m++) {
                int rbase = i0 + R0 + m * 16 + l4 * 4;
#pragma unroll
                for (int g = 0; g < 4; g++) {
                    size_t off = (size_t)(rbase + g) * C_ + col;
                    float z = acc[m][n][g] + bj;
                    z = z / (1.f + __expf(-z));
                    y1bf[off] = f2bf(z);
                }
            }
        }
    } else if (bid < 2560) {
        // ===== conv: depthwise K=31, LDS-staged weights, register sliding window =====
        int cb = bid - 2048;
        int tblk = cb & 63;
        int rest = cb >> 6;
        int b = rest >> 2;
        int c0 = (rest & 3) * 256;
        int t0 = tblk * TCV;
        float* wl = (float*)smem;
        for (int i = tid; i < 256 * KW_; i += 256) wl[i] = conv_w[c0 * KW_ + i];
        __syncthreads();
        float wr[KW_];
#pragma unroll
        for (int k = 0; k < KW_; k++) wr[k] = wl[tid * KW_ + k];
        int c = c0 + tid;
        float bi = conv_b[c];
        float acc[TCV];
#pragma unroll
        for (int t = 0; t < TCV; t++) acc[t] = bi;
        const short* xp = xbf + (size_t)b * T_ * C_ + c;
#pragma unroll
        for (int i = 0; i < TCV + KW_ - 1; i++) {
            int tt = t0 + i - 15;
            float xv = (tt >= 0 && tt < T_) ? bf2f(xp[(size_t)tt * C_]) : 0.f;
            int lo = (i - (KW_ - 1) > 0) ? i - (KW_ - 1) : 0;
            int hi = (i < TCV - 1) ? i : TCV - 1;
#pragma unroll
            for (int t = lo; t <= hi; t++)
                acc[t] = fmaf(xv, wr[i - t], acc[t]);
        }
        short* op = xconvb + ((size_t)b * T_ + t0) * C_ + c;
#pragma unroll
        for (int t = 0; t < TCV; t++) op[(size_t)t * C_] = f2bf(acc[t]);
    } else {
        // ===== w2 / w3 f32 -> bf16 (tail filler) =====
        int bid2 = bid - 2560;
        if (bid2 < 512) cvt8(w2, o2, bid2 * 256 + tid);
        else            cvt8(w3, o3, (bid2 - 512) * 256 + tid);
    }
}

// ---------------------------------------------------------------- bf16 MFMA GEMM  out = A(M,K)*W(N,K)^T
// tile 128x64, BK=64, double-buffered, counted-vmcnt + raw-barrier pipeline.
// MODE 1: comb epilogue with fused 2-chunk attn-combine (bf16 partials).
template <int MODE>
__global__ __launch_bounds__(256) void mgemm_kernel(
        const short* __restrict__ A, const short* __restrict__ W,
        const float* __restrict__ bias, short* __restrict__ outb,
        const short* __restrict__ e0, const short* __restrict__ e1,
        const short* __restrict__ e2, const float* __restrict__ e3,
        const short* __restrict__ partb, const float* __restrict__ lpart) {
    __shared__ short At[2 * 128 * 64];
    __shared__ short Wt[2 * 64 * 64];
    int tid = threadIdx.x;
    int w = tid >> 6, l = tid & 63;
    int l15 = l & 15, l4 = l >> 4;
    int i0 = ((int)blockIdx.x & 31) * 128;
    int j0 = ((int)blockIdx.x >> 5) * 64;
    int R0 = w * 32;
    int srow8 = l >> 3, sch = l & 7;
    const char* aptr[4];
#pragma unroll
    for (int q = 0; q < 4; q++) {
        int r = q * 32 + w * 8 + srow8;
        aptr[q] = (const char*)(A + (size_t)(i0 + r) * C_) + ((sch ^ (r & 7)) * 16);
    }
    const char* wptr[2];
#pragma unroll
    for (int q = 0; q < 2; q++) {
        int r = q * 32 + w * 8 + srow8;
        wptr[q] = (const char*)(W + (size_t)(j0 + r) * C_) + ((sch ^ (r & 7)) * 16);
    }
    char* Ab = (char*)At;
    char* Wb = (char*)Wt;

    f32x4 acc[2][4];
#pragma unroll
    for (int m = 0; m < 2; m++)
#pragma unroll
        for (int n = 0; n < 4; n++) acc[m][n] = (f32x4){0.f, 0.f, 0.f, 0.f};

#define GSTAGE(buf_, ks_) do {                                                 \
    size_t go_ = (size_t)(ks_) * 128;                                          \
    _Pragma("unroll") for (int q_ = 0; q_ < 4; q_++)                           \
        async16(aptr[q_] + go_, Ab + (buf_) * 16384 + q_ * 4096 + w * 1024);   \
    _Pragma("unroll") for (int q_ = 0; q_ < 2; q_++)                           \
        async16(wptr[q_] + go_, Wb + (buf_) * 8192 + q_ * 4096 + w * 1024);    \
} while (0)

    GSTAGE(0, 0);
    for (int ks = 0; ks < 16; ks++) {
        int buf = ks & 1;
        __builtin_amdgcn_s_barrier();
        if (ks + 1 < 16) {
            GSTAGE(buf ^ 1, ks + 1);
            asm volatile("s_waitcnt vmcnt(6)" ::: "memory");
        } else {
            asm volatile("s_waitcnt vmcnt(0)" ::: "memory");
        }
        __builtin_amdgcn_s_barrier();
        bf16x8 afr[2][2], bfr[4][2];
#pragma unroll
        for (int m = 0; m < 2; m++) {
            int r = R0 + m * 16 + l15;
#pragma unroll
            for (int s = 0; s < 2; s++)
                afr[m][s] = *(const bf16x8*)(Ab + buf * 16384 + r * 128 + (((s * 4 + l4) ^ (r & 7)) * 16));
        }
#pragma unroll
        for (int n = 0; n < 4; n++) {
            int r = n * 16 + l15;
#pragma unroll
            for (int s = 0; s < 2; s++)
                bfr[n][s] = *(const bf16x8*)(Wb + buf * 8192 + r * 128 + (((s * 4 + l4) ^ (r & 7)) * 16));
        }
        __builtin_amdgcn_s_setprio(1);
#pragma unroll
        for (int m = 0; m < 2; m++)
#pragma unroll
            for (int n = 0; n < 4; n++) {
                acc[m][n] = __builtin_amdgcn_mfma_f32_16x16x32_bf16(afr[m][0], bfr[n][0], acc[m][n], 0, 0, 0);
                acc[m][n] = __builtin_amdgcn_mfma_f32_16x16x32_bf16(afr[m][1], bfr[n][1], acc[m][n], 0, 0, 0);
            }
        __builtin_amdgcn_s_setprio(0);
    }
#undef GSTAGE
    // epilogue
    if (MODE == 1) {
        bool combrows = ((i0 & 2047) >= 1024);
        int b_ = i0 >> 11;
        int bh_ = b_ * 16 + (j0 >> 6);
#pragma unroll
        for (int m = 0; m < 2; m++) {
#pragma unroll
            for (int g = 0; g < 4; g++) {
                int row = i0 + R0 + m * 16 + l4 * 4 + g;
                int t_ = row & 2047;
                float xv[4];
                if (combrows) {
                    int s0_ = bh_ * 32 + (((t_ >> 6) - 16) << 1);
                    int r64 = t_ & 63;
                    float lt = lpart[(size_t)s0_ * 64 + r64] + lpart[(size_t)(s0_ + 1) * 64 + r64];
                    float li = 1.f / lt;
                    const short* p0 = partb + (size_t)s0_ * 4096 + r64 * 64;
                    const short* p1 = p0 + 4096;
#pragma unroll
                    for (int n = 0; n < 4; n++) {
                        int dv = n * 16 + l15;
                        xv[n] = (bf2f(p0[dv]) + bf2f(p1[dv])) * li;
                    }
                } else {
#pragma unroll
                    for (int n = 0; n < 4; n++)
                        xv[n] = bf2f(e1[(size_t)row * C_ + j0 + n * 16 + l15]);
                }
#pragma unroll
                for (int n = 0; n < 4; n++) {
                    int col = j0 + n * 16 + l15;
                    size_t off = (size_t)row * C_ + col;
                    float tdv = e3[col];
                    float z = acc[m][n][g] + bias[col];
                    float comb = bf2f(e0[off]) + 0.5f * xv[n] + 0.5f * z;
                    z = comb * tdv + bf2f(e2[off]) * (1.f - tdv);
                    outb[off] = f2bf(z);
                }
            }
        }
    } else {
#pragma unroll
        for (int n = 0; n < 4; n++) {
            int col = j0 + n * 16 + l15;
            float bj = bias[col];
#pragma unroll
            for (int m = 0; m < 2; m++) {
                int rbase = i0 + R0 + m * 16 + l4 * 4;
#pragma unroll
                for (int g = 0; g < 4; g++) {
                    size_t off = (size_t)(rbase + g) * C_ + col;
                    float z = acc[m][n][g] + bj;
                    if (MODE == 0) z = z / (1.f + __expf(-z));
                    outb[off] = f2bf(z);
                }
            }
        }
    }
}

// ---------------------------------------------------------------- layernorm + residual
__global__ __launch_bounds__(256) void ln_kernel(
        const short* __restrict__ proj, const short* __restrict__ xb,
        const float* __restrict__ g, const float* __restrict__ bb,
        float* __restrict__ out) {
    int row = blockIdx.x;
    int tid = threadIdx.x;
    const short* pr = proj + (size_t)row * C_;
    bf16x4 pv = *(const bf16x4*)(pr + tid * 4);
    float4 v = make_float4(bf2f(pv[0]), bf2f(pv[1]), bf2f(pv[2]), bf2f(pv[3]));
    float s = v.x + v.y + v.z + v.w;
    float s2 = v.x * v.x + v.y * v.y + v.z * v.z + v.w * v.w;
#pragma unroll
    for (int off = 32; off > 0; off >>= 1) {
        s += __shfl_down(s, off);
        s2 += __shfl_down(s2, off);
    }
    __shared__ float ws0[4], ws1[4];
    int wid = tid >> 6;
    if ((tid & 63) == 0) { ws0[wid] = s; ws1[wid] = s2; }
    __syncthreads();
    s = ws0[0] + ws0[1] + ws0[2] + ws0[3];
    s2 = ws1[0] + ws1[1] + ws1[2] + ws1[3];
    float mu = s * (1.f / C_);
    float var = s2 * (1.f / C_) - mu * mu;
    float rs = rsqrtf(var + 1e-5f);
    int c = tid * 4;
    bf16x4 xr4 = *(const bf16x4*)(xb + (size_t)row * C_ + c);
    float4 gg = *(const float4*)(g + c);
    float4 bv = *(const float4*)(bb + c);
    float4 o;
    o.x = (v.x - mu) * rs * gg.x + bv.x + bf2f(xr4[0]);
    o.y = (v.y - mu) * rs * gg.y + bv.y + bf2f(xr4[1]);
    o.z = (v.z - mu) * rs * gg.z + bv.z + bf2f(xr4[2]);
    o.w = (v.w - mu) * rs * gg.w + bv.w + bf2f(xr4[3]);
    *(float4*)(out + (size_t)row * C_ + c) = o;
}

// ---------------------------------------------------------------- launch
extern "C" void kernel_launch(void* const* d_in, const int* in_sizes, int n_in,
                              void* d_out, int out_size, void* d_ws, size_t ws_size,
                              hipStream_t stream) {
    const float* x      = (const float*)d_in[0];
    const float* conv_w = (const float*)d_in[1];
    const float* conv_b = (const float*)d_in[2];
    const float* q_w    = (const float*)d_in[3];
    const float* q_b    = (const float*)d_in[4];
    const float* kv_w   = (const float*)d_in[5];
    const float* kv_b   = (const float*)d_in[6];
    const float* mem_w1 = (const float*)d_in[7];
    const float* mem_b1 = (const float*)d_in[8];
    const float* mem_w2 = (const float*)d_in[9];
    const float* mem_b2 = (const float*)d_in[10];
    const float* out_w  = (const float*)d_in[11];
    const float* out_b  = (const float*)d_in[12];
    const float* ln_g   = (const float*)d_in[13];
    const float* ln_b   = (const float*)d_in[14];
    const float* td     = (const float*)d_in[15];
    float* out = (float*)d_out;

    const size_t NTC = (size_t)B_ * T_ * C_;
    char* p = (char*)d_ws;
    short* xconvb = (short*)p;           p += NTC * 2;
    short* xattb  = (short*)p;           p += NTC * 2;
    float* qb_   = (float*)p;            p += (size_t)B_ * T_ * 32 * 4;
    float* kbT   = (float*)p;            p += (size_t)B_ * H_ * 2 * T_ * 4;
    short* xbf   = (short*)p;            p += NTC * 2;
    short* y1bf  = (short*)p;            p += NTC * 2;
    short* combbf= (short*)p;            p += NTC * 2;
    short* xvt   = (short*)p;            p += NTC * 2;
    short* projb = (short*)p;            p += NTC * 2;
    short* wbf1  = (short*)p;            p += (size_t)C_ * C_ * 2;
    short* wbf2  = (short*)p;            p += (size_t)C_ * C_ * 2;
    short* wbf3  = (short*)p;            p += (size_t)C_ * C_ * 2;
    short* qkw   = (short*)p;            p += (size_t)64 * C_ * 2;
    short* partb = (short*)p;            p += (size_t)1024 * 4096 * 2;
    float* lpart = (float*)p;            p += (size_t)1024 * 64 * 4;

    prep_kernel<<<1568, 256, 0, stream>>>(x, xbf, xvt, mem_w1, wbf1, q_w, kv_w, qkw);
    qkproj_kernel<<<(B_ * T_) / 128, 256, 0, stream>>>(xbf, qkw, q_b, kv_b, qb_, kbT);
    mega_kernel<<<3584, 256, 0, stream>>>(qb_, kbT, xvt, xattb, partb, lpart,
                                          xbf, wbf1, mem_b1, y1bf,
                                          conv_w, conv_b, xconvb,
                                          mem_w2, out_w, wbf2, wbf3);
    mgemm_kernel<1><<<512, 256, 0, stream>>>(
        y1bf, wbf2, mem_b2, combbf, xconvb, xattb, xbf, td, partb, lpart);
    mgemm_kernel<2><<<512, 256, 0, stream>>>(
        combbf, wbf3, out_b, projb, nullptr, nullptr, nullptr, nullptr, nullptr, nullptr);
    ln_kernel<<<B_ * T_, 256, 0, stream>>>(projb, xbf, ln_g, ln_b, out);
}

// Round 21
// 121.929 us; speedup vs baseline: 1.0144x; 1.0129x over previous
//
#include <hip/hip_runtime.h>
#include <hip/hip_bf16.h>

#define B_ 2
#define T_ 2048
#define C_ 1024
#define H_ 16
#define DV_ 64
#define KW_ 31

typedef __attribute__((ext_vector_type(8))) short bf16x8;
typedef __attribute__((ext_vector_type(4))) short bf16x4;
typedef __attribute__((ext_vector_type(4))) float f32x4;

__device__ inline short f2bf(float f) {
    __hip_bfloat16 h = __float2bfloat16(f);
    return *reinterpret_cast<short*>(&h);
}
__device__ inline float bf2f(short s) {
    unsigned int u = ((unsigned int)(unsigned short)s) << 16;
    float f;
    __builtin_memcpy(&f, &u, 4);
    return f;
}

__device__ inline void async16(const void* g, void* l) {
    __builtin_amdgcn_global_load_lds(
        (const __attribute__((address_space(1))) unsigned int*)g,
        (__attribute__((address_space(3))) unsigned int*)l, 16, 0, 0);
}

__device__ inline void cvt8(const float* in, short* out, int i) {
    float4 v0 = ((const float4*)in)[i * 2];
    float4 v1 = ((const float4*)in)[i * 2 + 1];
    bf16x8 o;
    o[0] = f2bf(v0.x); o[1] = f2bf(v0.y); o[2] = f2bf(v0.z); o[3] = f2bf(v0.w);
    o[4] = f2bf(v1.x); o[5] = f2bf(v1.y); o[6] = f2bf(v1.z); o[7] = f2bf(v1.w);
    ((bf16x8*)out)[i] = o;
}

// ---------------------------------------------------------------- prep: xprep (0..1023) | w1 cvt (1024..1535) | qk pack (1536..1567)
__global__ __launch_bounds__(256) void prep_kernel(
        const float* __restrict__ x, short* __restrict__ xbf, short* __restrict__ xvt,
        const float* __restrict__ w1, short* __restrict__ o1,
        const float* __restrict__ qw, const float* __restrict__ kw,
        short* __restrict__ qkw) {
    int bid = blockIdx.x;
    int tid = threadIdx.x;
    if (bid < 1024) {
        int bh = bid >> 5;
        int b = bh >> 4, h = bh & 15;
        int t0 = (bid & 31) * 64;
        __shared__ float ldsT[64][65];
        int tl = tid >> 2;
        int d0 = (tid & 3) * 16;
        const float* xp = x + ((size_t)(b * T_ + t0 + tl)) * C_ + h * 64 + d0;
        short* xbp = xbf + ((size_t)(b * T_ + t0 + tl)) * C_ + h * 64 + d0;
#pragma unroll
        for (int q = 0; q < 4; q++) {
            float4 v = *(const float4*)(xp + q * 4);
            ldsT[d0 + q * 4 + 0][tl] = v.x;
            ldsT[d0 + q * 4 + 1][tl] = v.y;
            ldsT[d0 + q * 4 + 2][tl] = v.z;
            ldsT[d0 + q * 4 + 3][tl] = v.w;
            bf16x4 ob;
            ob[0] = f2bf(v.x); ob[1] = f2bf(v.y); ob[2] = f2bf(v.z); ob[3] = f2bf(v.w);
            *(bf16x4*)(xbp + q * 4) = ob;
        }
        __syncthreads();
        int d = tid >> 2;
        int ts = (tid & 3) * 16;
        short* op = xvt + ((size_t)bh * 64 + d) * T_ + t0 + ts;
        bf16x8 o0, o1;
#pragma unroll
        for (int q = 0; q < 8; q++) {
            o0[q] = f2bf(ldsT[d][ts + q]);
            o1[q] = f2bf(ldsT[d][ts + 8 + q]);
        }
        *(bf16x8*)op = o0;
        *(bf16x8*)(op + 8) = o1;
    } else if (bid < 1536) {
        cvt8(w1, o1, (bid - 1024) * 256 + tid);
    } else {
        int i = (bid - 1536) * 256 + tid;
        int n = i >> 7;
        int k8 = (i & 127) * 8;
        const float* src = (n < 32 ? qw + (size_t)n * C_ : kw + (size_t)(n - 32) * C_) + k8;
        float4 v0 = *(const float4*)src;
        float4 v1 = *(const float4*)(src + 4);
        bf16x8 o;
        o[0] = f2bf(v0.x); o[1] = f2bf(v0.y); o[2] = f2bf(v0.z); o[3] = f2bf(v0.w);
        o[4] = f2bf(v1.x); o[5] = f2bf(v1.y); o[6] = f2bf(v1.z); o[7] = f2bf(v1.w);
        ((bf16x8*)qkw)[i] = o;
    }
}

// ---------------------------------------------------------------- q/k proj via MFMA (bf16 inputs, global_load_lds staging)
__global__ __launch_bounds__(256) void qkproj_kernel(
        const short* __restrict__ A, const short* __restrict__ Wq,
        const float* __restrict__ qbias, const float* __restrict__ kbias,
        float* __restrict__ qo, float* __restrict__ kbT) {
    __shared__ short At[128 * 32];
    __shared__ short Wt[64 * 32];
    int tid = threadIdx.x;
    int w = tid >> 6, l = tid & 63;
    int i0 = blockIdx.x * 128;
    int R0 = w * 32;
    const int xorb = (((l >> 4) ^ (l & 3)) << 4);
    int srow = l >> 2, schunk = l & 3;

    f32x4 acc[2][4];
#pragma unroll
    for (int m = 0; m < 2; m++)
#pragma unroll
        for (int n = 0; n < 4; n++) acc[m][n] = (f32x4){0.f, 0.f, 0.f, 0.f};

    for (int k0 = 0; k0 < C_; k0 += 32) {
#pragma unroll
        for (int half = 0; half < 2; half++) {
            int rr = half * 64 + w * 16 + srow;
            int gch = schunk ^ (rr & 3);
            async16((const char*)(A + (size_t)(i0 + rr) * C_ + k0) + gch * 16,
                    (char*)At + half * 4096 + w * 1024);
        }
        {
            int rr = w * 16 + srow;
            int gch = schunk ^ (rr & 3);
            async16((const char*)(Wq + (size_t)rr * C_ + k0) + gch * 16,
                    (char*)Wt + w * 1024);
        }
        __syncthreads();
        bf16x8 afr[2], bfr[4];
#pragma unroll
        for (int m = 0; m < 2; m++)
            afr[m] = *(const bf16x8*)((char*)At + (R0 + m * 16 + (l & 15)) * 64 + xorb);
#pragma unroll
        for (int n = 0; n < 4; n++)
            bfr[n] = *(const bf16x8*)((char*)Wt + (n * 16 + (l & 15)) * 64 + xorb);
#pragma unroll
        for (int m = 0; m < 2; m++)
#pragma unroll
            for (int n = 0; n < 4; n++)
                acc[m][n] = __builtin_amdgcn_mfma_f32_16x16x32_bf16(afr[m], bfr[n], acc[m][n], 0, 0, 0);
        __syncthreads();
    }
#pragma unroll
    for (int n = 0; n < 4; n++) {
        int col = n * 16 + (l & 15);
        float bj = (col < 32) ? qbias[col] : kbias[col - 32];
#pragma unroll
        for (int m = 0; m < 2; m++) {
            int rbase = i0 + R0 + m * 16 + ((l >> 4) << 2);
#pragma unroll
            for (int g = 0; g < 4; g++) {
                float z = acc[m][n][g] + bj;
                int row = rbase + g;
                if (col < 32) {
                    qo[(size_t)row * 32 + col] = z;
                } else {
                    int cc = col - 32, hh = cc >> 1, dd = cc & 1;
                    int bb_ = row >> 11, tt = row & (T_ - 1);
                    kbT[(((size_t)bb_ * 16 + hh) * 2 + dd) * T_ + tt] = z;
                }
            }
        }
    }
}

// ---------------------------------------------------------------- MEGA: attn (0..1535) | mgemm0 (1536..2047) | conv (2048..3071) | w2/w3 cvt (3072..4095)
#define TCV 16
__global__ __launch_bounds__(256) void mega_kernel(
        const float* __restrict__ qbuf, const float* __restrict__ kbT,
        const short* __restrict__ xvt, short* __restrict__ xattb,
        short* __restrict__ partb, float* __restrict__ lpart,
        const short* __restrict__ xbf, const short* __restrict__ wbf1,
        const float* __restrict__ mem_b1, short* __restrict__ y1bf,
        const float* __restrict__ conv_w, const float* __restrict__ conv_b,
        short* __restrict__ xconvb,
        const float* __restrict__ w2, const float* __restrict__ w3,
        short* __restrict__ o2, short* __restrict__ o3) {
    __shared__ __align__(16) char smem[40960];
    int bid = blockIdx.x;
    int tid = threadIdx.x;
    int w = tid >> 6, l = tid & 63;
    int l15 = l & 15, l4 = l >> 4;

    if (bid < 1536) {
        // ===== attention, KV tile 128, KV-split CK=1024, no-max softmax =====
        int bh = bid & 31;
        int b = bh >> 4, h = bh & 15;
        int idx = 47 - (bid >> 5);
        int tb, ck;
        if (idx < 16) { tb = idx; ck = 0; }
        else          { tb = 16 + ((idx - 16) >> 1); ck = (idx - 16) & 1; }
        int t0 = tb * 64;
        int kvs = ck * 1024;
        int kve = min(kvs + 1024, t0 + 64);
        int ntiles = (kve - kvs + 127) >> 7;
        bool dom = (kve == t0 + 64);
        bool single = (tb < 16);
        char* Vb = smem;                      // 2 x 16KB
        char* Kb = smem + 32768;              // 8KB [2][1024] f32

        const float scale = 0.02209708691f * 1.44269504089f;  // 1/sqrt(T)*log2e
        int rloc = w * 16 + l15;
        float2 q2 = *(const float2*)(qbuf + ((size_t)(b * T_ + t0 + rloc)) * 32 + h * 2);
        float qx = q2.x * scale, qy = q2.y * scale;

        const uint4 onesu = {0x3F803F80u, 0x3F803F80u, 0x3F803F80u, 0x3F803F80u};
        bf16x8 ones = *(const bf16x8*)&onesu;

        f32x4 acc[4];
#pragma unroll
        for (int n = 0; n < 4; n++) acc[n] = (f32x4){0.f, 0.f, 0.f, 0.f};
        f32x4 acc_l = (f32x4){0.f, 0.f, 0.f, 0.f};

        // K chunk [2][1024] f32 staged once
        {
            int d = w >> 1, half = w & 1;
            char* kdst = Kb + d * 4096 + half * 2048;
            const char* ksrc = (const char*)(kbT + ((size_t)bh * 2 + d) * T_ + kvs)
                               + half * 2048 + l * 16;
            async16(ksrc, kdst);
            async16(ksrc + 1024, kdst + 1024);
        }
        // V staging: async j (0..3): dv = w*16 + j*4 + l4, slot = l15, src chunk c = l15 ^ (dv&15)
        const char* vsrc[4];
#pragma unroll
        for (int j = 0; j < 4; j++) {
            int dv = w * 16 + j * 4 + l4;
            int c = l15 ^ (dv & 15);
            vsrc[j] = (const char*)xvt + (((size_t)bh * 64 + dv) * T_ + (size_t)(kvs + c * 8)) * 2;
        }
#pragma unroll
        for (int j = 0; j < 4; j++)
            async16(vsrc[j], Vb + w * 4096 + j * 1024);

        const float* kl0 = (const float*)Kb;
        const float* kl1 = kl0 + 1024;

        for (int t = 0; t < ntiles; t++) {
            int buf = t & 1;
            __builtin_amdgcn_s_barrier();       // B1: prev reads of buf^1 done
            bool more = (t + 1 < ntiles);
            if (more) {
                size_t go = (size_t)((t + 1) * 128) * 2;
#pragma unroll
                for (int j = 0; j < 4; j++)
                    async16(vsrc[j] + go, Vb + (buf ^ 1) * 16384 + w * 4096 + j * 1024);
                asm volatile("s_waitcnt vmcnt(4)" ::: "memory");  // K + V(t) landed
            } else {
                asm volatile("s_waitcnt vmcnt(0)" ::: "memory");
            }
            __builtin_amdgcn_s_barrier();       // B2
            bool msk = dom && (t == ntiles - 1);
            int soff = kvs + t * 128 - t0;
            int locb = t * 128;
            bf16x8 afr[4];
#pragma unroll
            for (int ks = 0; ks < 4; ks++) {
                int lb = locb + ks * 32 + l4 * 8;
                float kx[8], ky[8];
                *(float4*)&kx[0] = *(const float4*)(kl0 + lb);
                *(float4*)&kx[4] = *(const float4*)(kl0 + lb + 4);
                *(float4*)&ky[0] = *(const float4*)(kl1 + lb);
                *(float4*)&ky[4] = *(const float4*)(kl1 + lb + 4);
                int kbase = soff + ks * 32 + l4 * 8;
                float pv[8];
#pragma unroll
                for (int i = 0; i < 8; i++) {
                    float sc = fmaf(qx, kx[i], qy * ky[i]);
                    float p = __builtin_amdgcn_exp2f(sc);
                    if (msk) p = (kbase + i <= rloc) ? p : 0.f;
                    pv[i] = p;
                }
                uint4 au;
                asm("v_cvt_pk_bf16_f32 %0, %1, %2" : "=v"(au.x) : "v"(pv[0]), "v"(pv[1]));
                asm("v_cvt_pk_bf16_f32 %0, %1, %2" : "=v"(au.y) : "v"(pv[2]), "v"(pv[3]));
                asm("v_cvt_pk_bf16_f32 %0, %1, %2" : "=v"(au.z) : "v"(pv[4]), "v"(pv[5]));
                asm("v_cvt_pk_bf16_f32 %0, %1, %2" : "=v"(au.w) : "v"(pv[6]), "v"(pv[7]));
                afr[ks] = *(bf16x8*)&au;
            }
            __builtin_amdgcn_s_setprio(1);
#pragma unroll
            for (int n = 0; n < 4; n++) {
                int dv = n * 16 + l15;
                int dvm = dv & 15;
#pragma unroll
                for (int ks = 0; ks < 4; ks++) {
                    int slot = (ks * 4 + l4) ^ dvm;
                    bf16x8 bv = *(const bf16x8*)(Vb + buf * 16384 + dv * 256 + slot * 16);
                    acc[n] = __builtin_amdgcn_mfma_f32_16x16x32_bf16(afr[ks], bv, acc[n], 0, 0, 0);
                }
            }
#pragma unroll
            for (int ks = 0; ks < 4; ks++)
                acc_l = __builtin_amdgcn_mfma_f32_16x16x32_bf16(afr[ks], ones, acc_l, 0, 0, 0);
            __builtin_amdgcn_s_setprio(0);
        }

        if (single) {
#pragma unroll
            for (int g = 0; g < 4; g++) {
                int row = w * 16 + l4 * 4 + g;
                float inv = 1.f / acc_l[g];
                int trow = t0 + row;
#pragma unroll
                for (int n = 0; n < 4; n++) {
                    int col = h * 64 + n * 16 + l15;
                    xattb[((size_t)(b * T_ + trow)) * C_ + col] = f2bf(acc[n][g] * inv);
                }
            }
        } else {
            int slot = bh * 32 + ((tb - 16) << 1) + ck;
            if (l15 == 0) {
#pragma unroll
                for (int g = 0; g < 4; g++)
                    lpart[(size_t)slot * 64 + w * 16 + l4 * 4 + g] = acc_l[g];
            }
            short* pp = partb + (size_t)slot * 4096;
#pragma unroll
            for (int g = 0; g < 4; g++) {
                int row = w * 16 + l4 * 4 + g;
#pragma unroll
                for (int n = 0; n < 4; n++)
                    pp[row * 64 + n * 16 + l15] = f2bf(acc[n][g]);
            }
        }
    } else if (bid < 2048) {
        // ===== mgemm0: y1 = silu(xbf*wbf1^T + b1), 128x64, BK=32, T4 pipeline =====
        int bid2 = bid - 1536;
        int i0 = (bid2 & 31) * 128;
        int j0 = (bid2 >> 5) * 64;
        int R0 = w * 32;
        const int xorb = ((l4 ^ (l & 3)) << 4);
        int srow = l >> 2, schunk = l & 3;
        char* Ab_ = smem;
        char* Wb_ = smem + 16384;

        f32x4 acc[2][4];
#pragma unroll
        for (int m = 0; m < 2; m++)
#pragma unroll
            for (int n = 0; n < 4; n++) acc[m][n] = (f32x4){0.f, 0.f, 0.f, 0.f};

#define GSTAGE0(buf_, k0_) do {                                                    \
    _Pragma("unroll") for (int half_ = 0; half_ < 2; half_++) {                    \
        int rr_ = half_ * 64 + w * 16 + srow;                                      \
        int gch_ = schunk ^ (rr_ & 3);                                             \
        async16((const char*)(xbf + (size_t)(i0 + rr_) * C_ + (k0_)) + gch_ * 16,  \
                Ab_ + (buf_) * 8192 + half_ * 4096 + w * 1024);                    \
    }                                                                              \
    { int rr_ = w * 16 + srow; int gch_ = schunk ^ (rr_ & 3);                      \
      async16((const char*)(wbf1 + (size_t)(j0 + rr_) * C_ + (k0_)) + gch_ * 16,   \
              Wb_ + (buf_) * 4096 + w * 1024); }                                   \
} while (0)

        GSTAGE0(0, 0);
        for (int ks = 0; ks < 32; ks++) {
            int buf = ks & 1;
            __builtin_amdgcn_s_barrier();
            if (ks + 1 < 32) {
                GSTAGE0(buf ^ 1, (ks + 1) * 32);
                asm volatile("s_waitcnt vmcnt(3)" ::: "memory");
            } else {
                asm volatile("s_waitcnt vmcnt(0)" ::: "memory");
            }
            __builtin_amdgcn_s_barrier();
            bf16x8 afr[2], bfr[4];
#pragma unroll
            for (int m = 0; m < 2; m++)
                afr[m] = *(const bf16x8*)(Ab_ + buf * 8192 + (R0 + m * 16 + l15) * 64 + xorb);
#pragma unroll
            for (int n = 0; n < 4; n++)
                bfr[n] = *(const bf16x8*)(Wb_ + buf * 4096 + (n * 16 + l15) * 64 + xorb);
            __builtin_amdgcn_s_setprio(1);
#pragma unroll
            for (int m = 0; m < 2; m++)
#pragma unroll
                for (int n = 0; n < 4; n++)
                    acc[m][n] = __builtin_amdgcn_mfma_f32_16x16x32_bf16(afr[m], bfr[n], acc[m][n], 0, 0, 0);
            __builtin_amdgcn_s_setprio(0);
        }
#undef GSTAGE0
#pragma unroll
        for (int n = 0; n < 4; n++) {
            int col = j0 + n * 16 + l15;
            float bj = mem_b1[col];
#pragma unroll
            for (int m = 0; m < 2; m++) {
                int rbase = i0 + R0 + m * 16 + l4 * 4;
#pragma unroll
                for (int g = 0; g < 4; g++) {
                    size_t off = (size_t)(rbase + g) * C_ + col;
                    float z = acc[m][n][g] + bj;
                    z = z / (1.f + __expf(-z));
                    y1bf[off] = f2bf(z);
                }
            }
        }
    } else if (bid < 3072) {
        // ===== conv: depthwise K=31, register sliding window =====
        int cb = bid - 2048;
        int tblk = cb & 127;
        int rest = cb >> 7;
        int b = rest >> 2;
        int c0 = (rest & 3) * 256;
        int t0 = tblk * TCV;
        int c = c0 + tid;
        float wr[KW_];
        const float* wp = conv_w + (size_t)c * KW_;
#pragma unroll
        for (int k = 0; k < KW_; k++) wr[k] = wp[k];
        float bi = conv_b[c];
        float acc[TCV];
#pragma unroll
        for (int t = 0; t < TCV; t++) acc[t] = bi;
        const short* xp = xbf + (size_t)b * T_ * C_ + c;
#pragma unroll
        for (int i = 0; i < TCV + KW_ - 1; i++) {
            int tt = t0 + i - 15;
            float xv = (tt >= 0 && tt < T_) ? bf2f(xp[(size_t)tt * C_]) : 0.f;
            int lo = (i - (KW_ - 1) > 0) ? i - (KW_ - 1) : 0;
            int hi = (i < TCV - 1) ? i : TCV - 1;
#pragma unroll
            for (int t = lo; t <= hi; t++)
                acc[t] = fmaf(xv, wr[i - t], acc[t]);
        }
        short* op = xconvb + ((size_t)b * T_ + t0) * C_ + c;
#pragma unroll
        for (int t = 0; t < TCV; t++) op[(size_t)t * C_] = f2bf(acc[t]);
    } else {
        // ===== w2 / w3 f32 -> bf16 (tail filler) =====
        int bid2 = bid - 3072;
        if (bid2 < 512) cvt8(w2, o2, bid2 * 256 + tid);
        else            cvt8(w3, o3, (bid2 - 512) * 256 + tid);
    }
}

// ---------------------------------------------------------------- bf16 MFMA GEMM  out = A(M,K)*W(N,K)^T
// tile 128x64, BK=64, double-buffered, counted-vmcnt + raw-barrier pipeline.
// MODE 1: comb epilogue with fused 2-chunk attn-combine (bf16 partials).
template <int MODE>
__global__ __launch_bounds__(256) void mgemm_kernel(
        const short* __restrict__ A, const short* __restrict__ W,
        const float* __restrict__ bias, short* __restrict__ outb,
        const short* __restrict__ e0, const short* __restrict__ e1,
        const short* __restrict__ e2, const float* __restrict__ e3,
        const short* __restrict__ partb, const float* __restrict__ lpart) {
    __shared__ short At[2 * 128 * 64];
    __shared__ short Wt[2 * 64 * 64];
    int tid = threadIdx.x;
    int w = tid >> 6, l = tid & 63;
    int l15 = l & 15, l4 = l >> 4;
    int i0 = ((int)blockIdx.x & 31) * 128;
    int j0 = ((int)blockIdx.x >> 5) * 64;
    int R0 = w * 32;
    int srow8 = l >> 3, sch = l & 7;
    const char* aptr[4];
#pragma unroll
    for (int q = 0; q < 4; q++) {
        int r = q * 32 + w * 8 + srow8;
        aptr[q] = (const char*)(A + (size_t)(i0 + r) * C_) + ((sch ^ (r & 7)) * 16);
    }
    const char* wptr[2];
#pragma unroll
    for (int q = 0; q < 2; q++) {
        int r = q * 32 + w * 8 + srow8;
        wptr[q] = (const char*)(W + (size_t)(j0 + r) * C_) + ((sch ^ (r & 7)) * 16);
    }
    char* Ab = (char*)At;
    char* Wb = (char*)Wt;

    f32x4 acc[2][4];
#pragma unroll
    for (int m = 0; m < 2; m++)
#pragma unroll
        for (int n = 0; n < 4; n++) acc[m][n] = (f32x4){0.f, 0.f, 0.f, 0.f};

#define GSTAGE(buf_, ks_) do {                                                 \
    size_t go_ = (size_t)(ks_) * 128;                                          \
    _Pragma("unroll") for (int q_ = 0; q_ < 4; q_++)                           \
        async16(aptr[q_] + go_, Ab + (buf_) * 16384 + q_ * 4096 + w * 1024);   \
    _Pragma("unroll") for (int q_ = 0; q_ < 2; q_++)                           \
        async16(wptr[q_] + go_, Wb + (buf_) * 8192 + q_ * 4096 + w * 1024);    \
} while (0)

    GSTAGE(0, 0);
    for (int ks = 0; ks < 16; ks++) {
        int buf = ks & 1;
        __builtin_amdgcn_s_barrier();
        if (ks + 1 < 16) {
            GSTAGE(buf ^ 1, ks + 1);
            asm volatile("s_waitcnt vmcnt(6)" ::: "memory");
        } else {
            asm volatile("s_waitcnt vmcnt(0)" ::: "memory");
        }
        __builtin_amdgcn_s_barrier();
        bf16x8 afr[2][2], bfr[4][2];
#pragma unroll
        for (int m = 0; m < 2; m++) {
            int r = R0 + m * 16 + l15;
#pragma unroll
            for (int s = 0; s < 2; s++)
                afr[m][s] = *(const bf16x8*)(Ab + buf * 16384 + r * 128 + (((s * 4 + l4) ^ (r & 7)) * 16));
        }
#pragma unroll
        for (int n = 0; n < 4; n++) {
            int r = n * 16 + l15;
#pragma unroll
            for (int s = 0; s < 2; s++)
                bfr[n][s] = *(const bf16x8*)(Wb + buf * 8192 + r * 128 + (((s * 4 + l4) ^ (r & 7)) * 16));
        }
        __builtin_amdgcn_s_setprio(1);
#pragma unroll
        for (int m = 0; m < 2; m++)
#pragma unroll
            for (int n = 0; n < 4; n++) {
                acc[m][n] = __builtin_amdgcn_mfma_f32_16x16x32_bf16(afr[m][0], bfr[n][0], acc[m][n], 0, 0, 0);
                acc[m][n] = __builtin_amdgcn_mfma_f32_16x16x32_bf16(afr[m][1], bfr[n][1], acc[m][n], 0, 0, 0);
            }
        __builtin_amdgcn_s_setprio(0);
    }
#undef GSTAGE
    // epilogue
    if (MODE == 1) {
        bool combrows = ((i0 & 2047) >= 1024);
        int b_ = i0 >> 11;
        int bh_ = b_ * 16 + (j0 >> 6);
#pragma unroll
        for (int m = 0; m < 2; m++) {
#pragma unroll
            for (int g = 0; g < 4; g++) {
                int row = i0 + R0 + m * 16 + l4 * 4 + g;
                int t_ = row & 2047;
                float xv[4];
                if (combrows) {
                    int s0_ = bh_ * 32 + (((t_ >> 6) - 16) << 1);
                    int r64 = t_ & 63;
                    float lt = lpart[(size_t)s0_ * 64 + r64] + lpart[(size_t)(s0_ + 1) * 64 + r64];
                    float li = 1.f / lt;
                    const short* p0 = partb + (size_t)s0_ * 4096 + r64 * 64;
                    const short* p1 = p0 + 4096;
#pragma unroll
                    for (int n = 0; n < 4; n++) {
                        int dv = n * 16 + l15;
                        xv[n] = (bf2f(p0[dv]) + bf2f(p1[dv])) * li;
                    }
                } else {
#pragma unroll
                    for (int n = 0; n < 4; n++)
                        xv[n] = bf2f(e1[(size_t)row * C_ + j0 + n * 16 + l15]);
                }
#pragma unroll
                for (int n = 0; n < 4; n++) {
                    int col = j0 + n * 16 + l15;
                    size_t off = (size_t)row * C_ + col;
                    float tdv = e3[col];
                    float z = acc[m][n][g] + bias[col];
                    float comb = bf2f(e0[off]) + 0.5f * xv[n] + 0.5f * z;
                    z = comb * tdv + bf2f(e2[off]) * (1.f - tdv);
                    outb[off] = f2bf(z);
                }
            }
        }
    } else {
#pragma unroll
        for (int n = 0; n < 4; n++) {
            int col = j0 + n * 16 + l15;
            float bj = bias[col];
#pragma unroll
            for (int m = 0; m < 2; m++) {
                int rbase = i0 + R0 + m * 16 + l4 * 4;
#pragma unroll
                for (int g = 0; g < 4; g++) {
                    size_t off = (size_t)(rbase + g) * C_ + col;
                    float z = acc[m][n][g] + bj;
                    if (MODE == 0) z = z / (1.f + __expf(-z));
                    outb[off] = f2bf(z);
                }
            }
        }
    }
}

// ---------------------------------------------------------------- layernorm + residual
__global__ __launch_bounds__(256) void ln_kernel(
        const short* __restrict__ proj, const short* __restrict__ xb,
        const float* __restrict__ g, const float* __restrict__ bb,
        float* __restrict__ out) {
    int row = blockIdx.x;
    int tid = threadIdx.x;
    const short* pr = proj + (size_t)row * C_;
    bf16x4 pv = *(const bf16x4*)(pr + tid * 4);
    float4 v = make_float4(bf2f(pv[0]), bf2f(pv[1]), bf2f(pv[2]), bf2f(pv[3]));
    float s = v.x + v.y + v.z + v.w;
    float s2 = v.x * v.x + v.y * v.y + v.z * v.z + v.w * v.w;
#pragma unroll
    for (int off = 32; off > 0; off >>= 1) {
        s += __shfl_down(s, off);
        s2 += __shfl_down(s2, off);
    }
    __shared__ float ws0[4], ws1[4];
    int wid = tid >> 6;
    if ((tid & 63) == 0) { ws0[wid] = s; ws1[wid] = s2; }
    __syncthreads();
    s = ws0[0] + ws0[1] + ws0[2] + ws0[3];
    s2 = ws1[0] + ws1[1] + ws1[2] + ws1[3];
    float mu = s * (1.f / C_);
    float var = s2 * (1.f / C_) - mu * mu;
    float rs = rsqrtf(var + 1e-5f);
    int c = tid * 4;
    bf16x4 xr4 = *(const bf16x4*)(xb + (size_t)row * C_ + c);
    float4 gg = *(const float4*)(g + c);
    float4 bv = *(const float4*)(bb + c);
    float4 o;
    o.x = (v.x - mu) * rs * gg.x + bv.x + bf2f(xr4[0]);
    o.y = (v.y - mu) * rs * gg.y + bv.y + bf2f(xr4[1]);
    o.z = (v.z - mu) * rs * gg.z + bv.z + bf2f(xr4[2]);
    o.w = (v.w - mu) * rs * gg.w + bv.w + bf2f(xr4[3]);
    *(float4*)(out + (size_t)row * C_ + c) = o;
}

// ---------------------------------------------------------------- launch
extern "C" void kernel_launch(void* const* d_in, const int* in_sizes, int n_in,
                              void* d_out, int out_size, void* d_ws, size_t ws_size,
                              hipStream_t stream) {
    const float* x      = (const float*)d_in[0];
    const float* conv_w = (const float*)d_in[1];
    const float* conv_b = (const float*)d_in[2];
    const float* q_w    = (const float*)d_in[3];
    const float* q_b    = (const float*)d_in[4];
    const float* kv_w   = (const float*)d_in[5];
    const float* kv_b   = (const float*)d_in[6];
    const float* mem_w1 = (const float*)d_in[7];
    const float* mem_b1 = (const float*)d_in[8];
    const float* mem_w2 = (const float*)d_in[9];
    const float* mem_b2 = (const float*)d_in[10];
    const float* out_w  = (const float*)d_in[11];
    const float* out_b  = (const float*)d_in[12];
    const float* ln_g   = (const float*)d_in[13];
    const float* ln_b   = (const float*)d_in[14];
    const float* td     = (const float*)d_in[15];
    float* out = (float*)d_out;

    const size_t NTC = (size_t)B_ * T_ * C_;
    char* p = (char*)d_ws;
    short* xconvb = (short*)p;           p += NTC * 2;
    short* xattb  = (short*)p;           p += NTC * 2;
    float* qb_   = (float*)p;            p += (size_t)B_ * T_ * 32 * 4;
    float* kbT   = (float*)p;            p += (size_t)B_ * H_ * 2 * T_ * 4;
    short* xbf   = (short*)p;            p += NTC * 2;
    short* y1bf  = (short*)p;            p += NTC * 2;
    short* combbf= (short*)p;            p += NTC * 2;
    short* xvt   = (short*)p;            p += NTC * 2;
    short* projb = (short*)p;            p += NTC * 2;
    short* wbf1  = (short*)p;            p += (size_t)C_ * C_ * 2;
    short* wbf2  = (short*)p;            p += (size_t)C_ * C_ * 2;
    short* wbf3  = (short*)p;            p += (size_t)C_ * C_ * 2;
    short* qkw   = (short*)p;            p += (size_t)64 * C_ * 2;
    short* partb = (short*)p;            p += (size_t)1024 * 4096 * 2;
    float* lpart = (float*)p;            p += (size_t)1024 * 64 * 4;

    prep_kernel<<<1568, 256, 0, stream>>>(x, xbf, xvt, mem_w1, wbf1, q_w, kv_w, qkw);
    qkproj_kernel<<<(B_ * T_) / 128, 256, 0, stream>>>(xbf, qkw, q_b, kv_b, qb_, kbT);
    mega_kernel<<<4096, 256, 0, stream>>>(qb_, kbT, xvt, xattb, partb, lpart,
                                          xbf, wbf1, mem_b1, y1bf,
                                          conv_w, conv_b, xconvb,
                                          mem_w2, out_w, wbf2, wbf3);
    mgemm_kernel<1><<<512, 256, 0, stream>>>(
        y1bf, wbf2, mem_b2, combbf, xconvb, xattb, xbf, td, partb, lpart);
    mgemm_kernel<2><<<512, 256, 0, stream>>>(
        combbf, wbf3, out_b, projb, nullptr, nullptr, nullptr, nullptr, nullptr, nullptr);
    ln_kernel<<<B_ * T_, 256, 0, stream>>>(projb, xbf, ln_g, ln_b, out);
}